// Round 1
// 3074.072 us; speedup vs baseline: 1.1871x; 1.1871x over previous
//
#include <hip/hip_runtime.h>

// ---------------- problem constants ----------------
constexpr int cB = 32, cS = 512, cH = 768, cL = 6, cNH = 12, cFF = 3072, cT = 7;
constexpr int cM = cB * cS;     // 16384 tokens
constexpr int cDH = cH / cNH;   // 64
constexpr int cQS = 2304;       // fused qkv row stride

#define DEVI __device__ __forceinline__

typedef __attribute__((ext_vector_type(8))) short bh8_t;          // 8 bf16 (4 VGPRs)
typedef __attribute__((ext_vector_type(4))) float f4_t;           // MFMA accumulator
typedef __attribute__((ext_vector_type(4))) unsigned short us4_t; // 4 bf16 (8B store)

DEVI unsigned short f2bf(float f) {
  unsigned int u = __float_as_uint(f);
  return (unsigned short)((u + 0x7fffu + ((u >> 16) & 1u)) >> 16);
}
DEVI float bf2f(unsigned short h) { return __uint_as_float(((unsigned int)h) << 16); }

// Abramowitz-Stegun 7.1.26, |abs err| < 1.5e-7 — far below the 16.48 threshold.
DEVI float fast_erff(float x) {
  const float a = fabsf(x);
  const float t = 1.0f / (1.0f + 0.3275911f * a);
  const float y = 1.0f - (((((1.061405429f * t - 1.453152027f) * t) + 1.421413741f) * t
                            - 0.284496736f) * t + 0.254829592f) * t * __expf(-a * a);
  return copysignf(y, x);
}

typedef __attribute__((address_space(1))) void* gas_t;
typedef __attribute__((address_space(3))) void* las_t;
DEVI void async16(void* lds, const void* g) {
  __builtin_amdgcn_global_load_lds((gas_t)g, (las_t)lds, 16, 0, 0);
}

// ---------------- batched weight transpose fp32(K,N) -> bf16(N,K) ----------------
struct WtransArgs { const float* src[6]; };

__global__ void wtrans_all(WtransArgs args, unsigned short* __restrict__ out) {
  const int m = blockIdx.z;
  const int K = (m == 5) ? cFF : cH;
  const int N = (m == 4) ? cFF : cH;
  int n0, k0;
  if (m < 4) {
    if (blockIdx.x >= 24) return;
    n0 = blockIdx.x * 32; k0 = blockIdx.y * 32;
  } else if (m == 4) {
    n0 = blockIdx.x * 32; k0 = blockIdx.y * 32;   // N=3072: bx<96
  } else {
    k0 = blockIdx.x * 32; n0 = blockIdx.y * 32;   // K=3072: bx<96
  }
  const int woffs[6] = {0, 589824, 1179648, 1769472, 2359296, 4718592};
  const float* in = args.src[m];
  unsigned short* o = out + woffs[m];
  __shared__ float tile[32][33];
  const int tx = threadIdx.x, ty = threadIdx.y;  // block (32,8)
#pragma unroll
  for (int i = 0; i < 4; i++)
    tile[ty + i * 8][tx] = in[(size_t)(k0 + ty + i * 8) * N + n0 + tx];
  __syncthreads();
#pragma unroll
  for (int i = 0; i < 4; i++)
    o[(size_t)(n0 + ty + i * 8) * K + k0 + tx] = f2bf(tile[tx][ty + i * 8]);
}

__global__ void concat_bias(const float* __restrict__ qb, const float* __restrict__ kb,
                            const float* __restrict__ vb, float* __restrict__ out) {
  const int c = blockIdx.x * 256 + threadIdx.x;  // 0..2303
  if (c < cQS)
    out[c] = c < cH ? qb[c] : (c < 2 * cH ? kb[c - cH] : vb[c - 2 * cH]);
}

// ---------------- 256x256 8-phase bf16 MFMA GEMM ----------------
// C(M,N) = A(M,K) * Bt(N,K)^T.  BM=BN=256, BK=64, 512 threads = 8 waves (2M x 4N),
// per-wave output 128x64. LDS 128 KiB: buf0 A @0, buf0 B @16384, buf1 A @32768,
// buf1 B @49152 (elems); each A/B tile is 2 halves of 8192 elems (128 rows x 64).
// Rows are 8 chunks of 8 bf16; LDS[row][phys] holds global chunk phys ^ (row&7)
// (source-permuted so global_load_lds dest stays lane-contiguous); fragment
// ds_read_b128 then land on the free 2-way bank floor (phys = (ks*4+quad)^(col&7)).
// 8-phase schedule, counted vmcnt(6) at phases 0/4 (never 0 mid-loop); stagger:
//   ph0: A0(t+1)  ph1: A1(t+1)  ph2: B0(t+2)  ph3: B1(t+2)
//   ph4: A0(t+2)  ph5: A1(t+2)  ph6: B0(t+3)  ph7: B1(t+3)
// Each stage writes a region whose last reader closed >=1 barrier earlier; the
// vmcnt(6) at a tile boundary leaves exactly the 3 newest half-tiles in flight,
// guaranteeing the tile about to be consumed has fully landed.
// Even tiles always live in buf0, odd in buf1 (loop steps tiles in pairs).

DEVI void stage_half(unsigned short* half_lds, const unsigned short* g0, int K, int tid) {
#pragma unroll
  for (int j = 0; j < 2; ++j) {
    const int cid = j * 512 + tid;          // chunk id 0..1023
    const int row = cid >> 3;               // 0..127
    const int sc = (cid & 7) ^ (row & 7);   // source k-chunk (inverse swizzle)
    async16(half_lds + (size_t)(j * 512 + (tid & ~63)) * 8,   // wave-uniform dest
            g0 + (size_t)row * K + sc * 8);
  }
}

DEVI void load_a4(bh8_t (&dst)[4][2], const unsigned short* base, const int pq[2]) {
#pragma unroll
  for (int mi = 0; mi < 4; ++mi)
#pragma unroll
    for (int ks = 0; ks < 2; ++ks)
      dst[mi][ks] = *(const bh8_t*)(base + mi * 1024 + pq[ks]);
}

DEVI void load_b2(bh8_t (&dst)[2][2], const unsigned short* base, const int pq[2]) {
#pragma unroll
  for (int ni = 0; ni < 2; ++ni)
#pragma unroll
    for (int ks = 0; ks < 2; ++ks)
      dst[ni][ks] = *(const bh8_t*)(base + ni * 1024 + pq[ks]);
}

template <int NI0, int MI0>
DEVI void qmfma(f4_t (&acc)[8][4], const bh8_t (&bset)[2][2], const bh8_t (&af)[4][2]) {
#pragma unroll
  for (int mi = 0; mi < 4; ++mi)
#pragma unroll
    for (int ks = 0; ks < 2; ++ks) {  // swapped operands -> C^T fragment layout
      acc[MI0 + mi][NI0] = __builtin_amdgcn_mfma_f32_16x16x32_bf16(
          bset[0][ks], af[mi][ks], acc[MI0 + mi][NI0], 0, 0, 0);
      acc[MI0 + mi][NI0 + 1] = __builtin_amdgcn_mfma_f32_16x16x32_bf16(
          bset[1][ks], af[mi][ks], acc[MI0 + mi][NI0 + 1], 0, 0, 0);
    }
}

DEVI void wgbar() {
  asm volatile("" ::: "memory");
  __builtin_amdgcn_s_barrier();
  asm volatile("" ::: "memory");
}

template <bool RESID, bool GELU, bool OUTB>
__global__ __launch_bounds__(512, 2) void gemm256(
    const unsigned short* __restrict__ A, const unsigned short* __restrict__ Bt,
    const float* __restrict__ bias, const float* resid,
    float* outf, unsigned short* __restrict__ outb, int N, int K) {
  __shared__ __align__(16) unsigned short lds[65536];  // 128 KB
  const int tid = threadIdx.x;
  const int lane = tid & 63, wave = tid >> 6;
  const int wm = wave >> 2, wn = wave & 3;
  const int quad = lane >> 4, col = lane & 15;
  const int m0 = blockIdx.y * 256, n0 = blockIdx.x * 256;
  const int nt = K >> 6;  // K tiles of 64 (K=768 -> 12, K=3072 -> 48; always even)

  const unsigned short* Ag = A + (size_t)m0 * K;
  const unsigned short* Bg = Bt + (size_t)n0 * K;

  // fragment read bases (elems). row&7 == col&7 for every fragment row.
  const int aoff = wm * 8192 + col * 64;
  const int boff = 16384 + (wn >> 1) * 8192 + (wn & 1) * 4096 + col * 64;
  const int pq[2] = {(quad ^ (col & 7)) * 8, ((quad + 4) ^ (col & 7)) * 8};

  f4_t acc[8][4] = {};
  bh8_t af[4][2], blo[2][2], bhi[2][2];

  // prologue: B(0), A(0), B(1)  (12 loads/thread; order matters for vmcnt math)
  stage_half(lds + 16384, Bg, K, tid);
  stage_half(lds + 16384 + 8192, Bg + (size_t)128 * K, K, tid);
  stage_half(lds + 0, Ag, K, tid);
  stage_half(lds + 8192, Ag + (size_t)128 * K, K, tid);
  stage_half(lds + 49152, Bg + 64, K, tid);
  stage_half(lds + 49152 + 8192, Bg + (size_t)128 * K + 64, K, tid);

  for (int t = 0; t < nt; t += 2) {
    const bool tail = (t + 2 >= nt);
    const size_t k1 = (size_t)(t + 1) << 6;
    const size_t k2 = (size_t)(t + 2) << 6;
    const size_t k3 = (size_t)(t + 3) << 6;

    // ---- phase 0: tile t (buf0), b-lo + a-lo ----
    stage_half(lds + 32768, Ag + k1, K, tid);
    asm volatile("s_waitcnt vmcnt(6)" ::: "memory");
    wgbar();
    load_b2(blo, lds + boff, pq);
    load_a4(af, lds + aoff, pq);
    asm volatile("s_waitcnt lgkmcnt(0)" ::: "memory");
    __builtin_amdgcn_s_setprio(1);
    qmfma<0, 0>(acc, blo, af);
    __builtin_amdgcn_s_setprio(0);
    wgbar();

    // ---- phase 1: b-hi ----
    load_b2(bhi, lds + boff + 2048, pq);
    stage_half(lds + 32768 + 8192, Ag + (size_t)128 * K + k1, K, tid);
    wgbar();
    asm volatile("s_waitcnt lgkmcnt(0)" ::: "memory");
    __builtin_amdgcn_s_setprio(1);
    qmfma<2, 0>(acc, bhi, af);
    __builtin_amdgcn_s_setprio(0);
    wgbar();

    // ---- phase 2: a-hi ----
    load_a4(af, lds + aoff + 4096, pq);
    if (!tail) stage_half(lds + 16384, Bg + k2, K, tid);
    wgbar();
    asm volatile("s_waitcnt lgkmcnt(0)" ::: "memory");
    __builtin_amdgcn_s_setprio(1);
    qmfma<0, 4>(acc, blo, af);
    __builtin_amdgcn_s_setprio(0);
    wgbar();

    // ---- phase 3: pure MFMA ----
    if (!tail) stage_half(lds + 16384 + 8192, Bg + (size_t)128 * K + k2, K, tid);
    wgbar();
    __builtin_amdgcn_s_setprio(1);
    qmfma<2, 4>(acc, bhi, af);
    __builtin_amdgcn_s_setprio(0);
    wgbar();

    // ---- phase 4: tile t+1 (buf1), b-lo + a-lo ----
    if (!tail) stage_half(lds + 0, Ag + k2, K, tid);
    if (tail) { asm volatile("s_waitcnt vmcnt(0)" ::: "memory"); }
    else      { asm volatile("s_waitcnt vmcnt(6)" ::: "memory"); }
    wgbar();
    load_b2(blo, lds + 32768 + boff, pq);
    load_a4(af, lds + 32768 + aoff, pq);
    asm volatile("s_waitcnt lgkmcnt(0)" ::: "memory");
    __builtin_amdgcn_s_setprio(1);
    qmfma<0, 0>(acc, blo, af);
    __builtin_amdgcn_s_setprio(0);
    wgbar();

    // ---- phase 5: b-hi ----
    load_b2(bhi, lds + 32768 + boff + 2048, pq);
    if (!tail) stage_half(lds + 8192, Ag + (size_t)128 * K + k2, K, tid);
    wgbar();
    asm volatile("s_waitcnt lgkmcnt(0)" ::: "memory");
    __builtin_amdgcn_s_setprio(1);
    qmfma<2, 0>(acc, bhi, af);
    __builtin_amdgcn_s_setprio(0);
    wgbar();

    // ---- phase 6: a-hi ----
    load_a4(af, lds + 32768 + aoff + 4096, pq);
    if (!tail) stage_half(lds + 49152, Bg + k3, K, tid);
    wgbar();
    asm volatile("s_waitcnt lgkmcnt(0)" ::: "memory");
    __builtin_amdgcn_s_setprio(1);
    qmfma<0, 4>(acc, blo, af);
    __builtin_amdgcn_s_setprio(0);
    wgbar();

    // ---- phase 7: pure MFMA ----
    if (!tail) stage_half(lds + 49152 + 8192, Bg + (size_t)128 * K + k3, K, tid);
    wgbar();
    __builtin_amdgcn_s_setprio(1);
    qmfma<2, 4>(acc, bhi, af);
    __builtin_amdgcn_s_setprio(0);
    wgbar();
  }

  // epilogue: lane holds rows m = wm*128 + mi*16 + col, cols n = wn*64 + ni*16 + quad*4 + r
#pragma unroll
  for (int mi = 0; mi < 8; ++mi) {
    const size_t rowbase = (size_t)(m0 + wm * 128 + mi * 16 + col) * N;
#pragma unroll
    for (int ni = 0; ni < 4; ++ni) {
      const int cb = n0 + wn * 64 + ni * 16 + quad * 4;
      f4_t v = acc[mi][ni] + *(const f4_t*)(bias + cb);
      if (RESID) v += *(const f4_t*)(resid + rowbase + cb);
      if (GELU) {
#pragma unroll
        for (int r = 0; r < 4; r++)
          v[r] = 0.5f * v[r] * (1.0f + fast_erff(v[r] * 0.70710678118654752f));
      }
      if (OUTB) {
        us4_t u;
#pragma unroll
        for (int r = 0; r < 4; r++) u[r] = f2bf(v[r]);
        *(us4_t*)(outb + rowbase + cb) = u;
      } else {
        *(f4_t*)(outf + rowbase + cb) = v;
      }
    }
  }
}

// ---------------- embedding + LayerNorm (fused) ----------------
__global__ __launch_bounds__(256) void embed_ln(
    const int* __restrict__ ids, const float* __restrict__ wemb,
    const float* __restrict__ pemb, const float* __restrict__ g,
    const float* __restrict__ be, float* __restrict__ xo,
    unsigned short* __restrict__ xbo) {
  const int token = blockIdx.x;
  const int tid = threadIdx.x;
  const int id = ids[token];
  const int pos = token & (cS - 1);
  const float* wr = wemb + (size_t)id * cH;
  const float* pr = pemb + (size_t)pos * cH;
  float v[3];
#pragma unroll
  for (int i = 0; i < 3; i++) v[i] = wr[tid + i * 256] + pr[tid + i * 256];
  float s = v[0] + v[1] + v[2];
  float s2 = v[0] * v[0] + v[1] * v[1] + v[2] * v[2];
#pragma unroll
  for (int off = 32; off; off >>= 1) { s += __shfl_xor(s, off); s2 += __shfl_xor(s2, off); }
  __shared__ float sa[4], sb[4];
  if ((tid & 63) == 0) { sa[tid >> 6] = s; sb[tid >> 6] = s2; }
  __syncthreads();
  s = sa[0] + sa[1] + sa[2] + sa[3];
  s2 = sb[0] + sb[1] + sb[2] + sb[3];
  const float mean = s * (1.0f / cH);
  const float rstd = rsqrtf(s2 * (1.0f / cH) - mean * mean + 1e-12f);
  float* xr = xo + (size_t)token * cH;
  unsigned short* xbr = xbo + (size_t)token * cH;
#pragma unroll
  for (int i = 0; i < 3; i++) {
    const int c = tid + i * 256;
    const float nv = (v[i] - mean) * rstd * g[c] + be[c];
    xr[c] = nv;
    xbr[c] = f2bf(nv);
  }
}

// ---------------- in-place LayerNorm: x -> x (fp32) + xb (bf16) ----------------
__global__ __launch_bounds__(256) void ln_fused(
    float* __restrict__ x, const float* __restrict__ g,
    const float* __restrict__ be, unsigned short* __restrict__ xbo) {
  const int token = blockIdx.x;
  const int tid = threadIdx.x;
  float* row = x + (size_t)token * cH;
  float v[3];
#pragma unroll
  for (int i = 0; i < 3; i++) v[i] = row[tid + i * 256];
  float s = v[0] + v[1] + v[2];
  float s2 = v[0] * v[0] + v[1] * v[1] + v[2] * v[2];
#pragma unroll
  for (int off = 32; off; off >>= 1) { s += __shfl_xor(s, off); s2 += __shfl_xor(s2, off); }
  __shared__ float sa[4], sb[4];
  if ((tid & 63) == 0) { sa[tid >> 6] = s; sb[tid >> 6] = s2; }
  __syncthreads();
  s = sa[0] + sa[1] + sa[2] + sa[3];
  s2 = sb[0] + sb[1] + sb[2] + sb[3];
  const float mean = s * (1.0f / cH);
  const float rstd = rsqrtf(s2 * (1.0f / cH) - mean * mean + 1e-12f);
  unsigned short* xbr = xbo + (size_t)token * cH;
#pragma unroll
  for (int i = 0; i < 3; i++) {
    const int c = tid + i * 256;
    const float nv = (v[i] - mean) * rstd * g[c] + be[c];
    row[c] = nv;
    xbr[c] = f2bf(nv);
  }
}

// ---------------- flash attention, MFMA 16x16x32 bf16 (fused qkv input) -------
__global__ __launch_bounds__(256, 2) void attn_mfma(
    const unsigned short* __restrict__ qkv, const int* __restrict__ amask,
    unsigned short* __restrict__ ctxb) {
  __shared__ __align__(16) unsigned short Ks[128 * 64];   // [key][physblk*8+j]
  __shared__ __align__(16) unsigned short Vt[64 * 128];   // [d][physblk*8 + key&7]
  __shared__ __align__(16) unsigned short Ps[4 * 32 * 136];
  __shared__ int lensh[4];

  const int tid = threadIdx.x, lane = tid & 63, wave = tid >> 6;
  const int quad = lane >> 4, col = lane & 15;
  const int wg = blockIdx.x;
  const int qb = wg & 3, h = (wg >> 2) % cNH, b = wg / (4 * cNH);
  const int q0 = qb * 128 + wave * 32;  // this wave's first query

  const unsigned short* qg = qkv;
  const unsigned short* kg = qkv + cH;
  const unsigned short* vg = qkv + 2 * cH;

  // sequence length (WG-uniform)
  const int* mrow = amask + b * cS;
  int c = mrow[tid] + mrow[tid + 256];
#pragma unroll
  for (int off = 32; off; off >>= 1) c += __shfl_xor(c, off);
  if (lane == 0) lensh[wave] = c;
  __syncthreads();
  const int len = lensh[0] + lensh[1] + lensh[2] + lensh[3];

  // resident Q fragments (A-operand), 32 queries x 64 d
  const unsigned short* qbase = qg + (size_t)(b * cS + q0) * cQS + h * cDH;
  bh8_t qf[2][2];
#pragma unroll
  for (int mi = 0; mi < 2; mi++)
#pragma unroll
    for (int ks = 0; ks < 2; ks++)
      qf[mi][ks] = *(const bh8_t*)(qbase + (size_t)(mi * 16 + col) * cQS + ks * 32 + quad * 8);

  float mr[2][4], lr[2][4];
  f4_t o[2][4] = {};
#pragma unroll
  for (int mi = 0; mi < 2; mi++)
#pragma unroll
    for (int r = 0; r < 4; r++) { mr[mi][r] = -3.0e38f; lr[mi][r] = 0.0f; }

  unsigned short* Pw = Ps + wave * (32 * 136);

  for (int k0 = 0; k0 < cS; k0 += 128) {
    if (k0 >= len) break;  // remaining tiles fully masked (len WG-uniform)
    __syncthreads();       // prior iter's Ks/Vt reads complete before restage
    const unsigned short* kb = kg + (size_t)(b * cS + k0) * cQS + h * cDH;
    const unsigned short* vb = vg + (size_t)(b * cS + k0) * cQS + h * cDH;
    // K: async16, LDS(key, physblk) <- global d-block (physblk ^ (key&7))
#pragma unroll
    for (int i = 0; i < 4; i++) {
      const int chunk = i * 256 + tid;
      const int key = chunk >> 3;
      const int ld = (chunk & 7) ^ (key & 7);
      async16(Ks + (size_t)(i * 256 + wave * 64) * 8, kb + (size_t)key * cQS + ld * 8);
    }
    // V: manual transpose, Vt[d][pb*8 + key&7], pb = keyblk ^ (d&7) ^ (d>>3)
#pragma unroll
    for (int i = 0; i < 4; i++) {
      const int chunk = i * 256 + tid;
      const int key = chunk >> 3;
      const int ld = chunk & 7;
      const int bk = key >> 3;
      bh8_t vv = *(const bh8_t*)(vb + (size_t)key * cQS + ld * 8);
      unsigned short vs[8];
      *(bh8_t*)vs = vv;
#pragma unroll
      for (int j = 0; j < 8; j++) {
        const int d = ld * 8 + j;
        const int pb = bk ^ j ^ ld;
        Vt[d * 128 + pb * 8 + (key & 7)] = vs[j];
      }
    }
    __syncthreads();  // staging visible (drains vmcnt+lgkmcnt)

    // S = Q K^T (32 q x 128 k per wave)
    f4_t s[2][8];
#pragma unroll
    for (int mi = 0; mi < 2; mi++)
#pragma unroll
      for (int n = 0; n < 8; n++) s[mi][n] = f4_t{0.f, 0.f, 0.f, 0.f};
#pragma unroll
    for (int n = 0; n < 8; n++) {
      const int r = n * 16 + col;  // key row
#pragma unroll
      for (int ks = 0; ks < 2; ks++) {
        const int phys = (ks * 4 + quad) ^ (col & 7);
        bh8_t kf = *(const bh8_t*)(Ks + (size_t)r * 64 + phys * 8);
        s[0][n] = __builtin_amdgcn_mfma_f32_16x16x32_bf16(qf[0][ks], kf, s[0][n], 0, 0, 0);
        s[1][n] = __builtin_amdgcn_mfma_f32_16x16x32_bf16(qf[1][ks], kf, s[1][n], 0, 0, 0);
      }
    }
    // scale + mask
#pragma unroll
    for (int n = 0; n < 8; n++) {
      const bool valid = (k0 + n * 16 + col) < len;
#pragma unroll
      for (int mi = 0; mi < 2; mi++)
#pragma unroll
        for (int r = 0; r < 4; r++)
          s[mi][n][r] = valid ? s[mi][n][r] * 0.125f : -3.0e38f;
    }
    // online softmax per query row (row lives on 16 lanes of one quad)
#pragma unroll
    for (int mi = 0; mi < 2; mi++)
#pragma unroll
      for (int r = 0; r < 4; r++) {
        float v = s[mi][0][r];
#pragma unroll
        for (int n = 1; n < 8; n++) v = fmaxf(v, s[mi][n][r]);
#pragma unroll
        for (int off = 1; off < 16; off <<= 1) v = fmaxf(v, __shfl_xor(v, off));
        const float nm = fmaxf(mr[mi][r], v);
        const float alpha = __expf(mr[mi][r] - nm);
        float rs = 0.0f;
#pragma unroll
        for (int n = 0; n < 8; n++) {
          const float p = __expf(s[mi][n][r] - nm);
          s[mi][n][r] = p;
          rs += p;
        }
#pragma unroll
        for (int off = 1; off < 16; off <<= 1) rs += __shfl_xor(rs, off);
        lr[mi][r] = lr[mi][r] * alpha + rs;
        mr[mi][r] = nm;
#pragma unroll
        for (int nd = 0; nd < 4; nd++) o[mi][nd][r] *= alpha;
      }
    // P -> LDS (C-layout write), then A-frag reads
#pragma unroll
    for (int mi = 0; mi < 2; mi++)
#pragma unroll
      for (int n = 0; n < 8; n++)
#pragma unroll
        for (int r = 0; r < 4; r++)
          Pw[(mi * 16 + quad * 4 + r) * 136 + n * 16 + col] = f2bf(s[mi][n][r]);
    __syncthreads();
    // O += P V
#pragma unroll
    for (int ks = 0; ks < 4; ks++) {
      bh8_t pf[2];
#pragma unroll
      for (int mi = 0; mi < 2; mi++)
        pf[mi] = *(const bh8_t*)(Pw + (size_t)(mi * 16 + col) * 136 + ks * 32 + quad * 8);
#pragma unroll
      for (int nd = 0; nd < 4; nd++) {
        const int d = nd * 16 + col;
        const int pb = (ks * 4 + quad) ^ (d & 7) ^ (d >> 3);
        bh8_t vf = *(const bh8_t*)(Vt + (size_t)d * 128 + pb * 8);
        o[0][nd] = __builtin_amdgcn_mfma_f32_16x16x32_bf16(pf[0], vf, o[0][nd], 0, 0, 0);
        o[1][nd] = __builtin_amdgcn_mfma_f32_16x16x32_bf16(pf[1], vf, o[1][nd], 0, 0, 0);
      }
    }
  }

  // epilogue: normalize and store ctx (bf16)
#pragma unroll
  for (int mi = 0; mi < 2; mi++)
#pragma unroll
    for (int r = 0; r < 4; r++) {
      const float inv = 1.0f / lr[mi][r];  // len >= 256 so lr > 0
      const int q = q0 + mi * 16 + quad * 4 + r;
      unsigned short* orow = ctxb + (size_t)(b * cS + q) * cH + h * cDH;
#pragma unroll
      for (int nd = 0; nd < 4; nd++) orow[nd * 16 + col] = f2bf(o[mi][nd][r] * inv);
    }
}

// ---------------- classifier head: emissions = x @ cls_w + cls_b ----------------
__global__ __launch_bounds__(256) void cls_head(
    const float* __restrict__ x, const float* __restrict__ w,
    const float* __restrict__ cb, float* __restrict__ em) {
  const int token = blockIdx.x * 4 + (threadIdx.x >> 6);
  const int lane = threadIdx.x & 63;
  const float* xr = x + (size_t)token * cH;
  float p[cT] = {};
  for (int k = lane; k < cH; k += 64) {
    const float xv = xr[k];
    const float* wr = w + k * cT;
#pragma unroll
    for (int t = 0; t < cT; t++) p[t] += xv * wr[t];
  }
#pragma unroll
  for (int t = 0; t < cT; t++) {
    float r = p[t];
#pragma unroll
    for (int off = 32; off; off >>= 1) r += __shfl_xor(r, off);
    if (lane == t) em[(size_t)token * cT + t] = r + cb[t];
  }
}

// ---------------- CRF NLL: chunked log-semiring scan, one block per sequence ----
__global__ __launch_bounds__(1024) void crf(
    const float* __restrict__ em, const int* __restrict__ labels,
    const float* __restrict__ cstart, const float* __restrict__ cend,
    const float* __restrict__ ctrans, float* __restrict__ out) {
  const int b = blockIdx.x;
  const int tid = threadIdx.x;
  const int wave = tid >> 6, lane = tid & 63;
  const int* lab = labels + b * cS;
  const float* eb = em + (size_t)b * cS * cT;

  __shared__ float mats[16][49];
  __shared__ float mbuf[8][49];
  __shared__ int slen;
  __shared__ float snum;
  if (tid == 0) { slen = 0; snum = 0.0f; }
  __syncthreads();

  if (tid < cS) {
    const int valid = (tid == 0) || (lab[tid] != -100);
    const unsigned long long bal = __ballot(valid);
    if (lane == 0) atomicAdd(&slen, __popcll(bal));
  }
  __syncthreads();
  const int len = slen;

  {
    float np = 0.0f;
    if (tid >= 1 && tid < len)
      np = ctrans[lab[tid - 1] * cT + lab[tid]] + eb[tid * cT + lab[tid]];
#pragma unroll
    for (int off = 32; off; off >>= 1) np += __shfl_xor(np, off);
    if (lane == 0) atomicAdd(&snum, np);
  }

  const int ii = (lane < 49) ? lane / 7 : 0;
  const int jj = (lane < 49) ? lane % 7 : 0;
  const int i7 = ii * 7;
  float trk[cT];
#pragma unroll
  for (int k = 0; k < cT; k++) trk[k] = ctrans[k * cT + jj];

  float Nij = (ii == jj) ? 0.0f : -1.0e30f;  // log-semiring identity
  const int s_beg = 1 + 32 * wave;
  const int s_end = min(s_beg + 32, len);
  for (int s = s_beg; s < s_end; s++) {
    const float ej = eb[s * cT + jj];
    float v[cT];
#pragma unroll
    for (int k = 0; k < cT; k++) v[k] = __shfl(Nij, i7 + k) + trk[k];
    float mx = v[0];
#pragma unroll
    for (int k = 1; k < cT; k++) mx = fmaxf(mx, v[k]);
    float ss = 0.0f;
#pragma unroll
    for (int k = 0; k < cT; k++) ss += __expf(v[k] - mx);
    Nij = mx + __logf(ss) + ej;
  }
  if (lane < 49) mats[wave][lane] = Nij;
  __syncthreads();

  auto compose = [&](const float* Am, const float* Bm) -> float {
    float v[cT];
#pragma unroll
    for (int k = 0; k < cT; k++) v[k] = Am[i7 + k] + Bm[k * 7 + jj];
    float mx = v[0];
#pragma unroll
    for (int k = 1; k < cT; k++) mx = fmaxf(mx, v[k]);
    float ss = 0.0f;
#pragma unroll
    for (int k = 0; k < cT; k++) ss += __expf(v[k] - mx);
    return mx + __logf(ss);
  };
  if (wave < 8 && lane < 49) mbuf[wave][lane] = compose(mats[2 * wave], mats[2 * wave + 1]);
  __syncthreads();
  if (wave < 4 && lane < 49) mats[wave][lane] = compose(mbuf[2 * wave], mbuf[2 * wave + 1]);
  __syncthreads();
  if (wave < 2 && lane < 49) mbuf[wave][lane] = compose(mats[2 * wave], mats[2 * wave + 1]);
  __syncthreads();

  if (wave == 0) {
    float Mij = compose(mbuf[0], mbuf[1]);
    const float a0 = cstart[ii] + eb[ii];
    const float t = a0 + Mij;
    float av[cT];
#pragma unroll
    for (int k = 0; k < cT; k++) av[k] = __shfl(t, k * 7 + lane);  // valid for lane<7
    float mx = av[0];
#pragma unroll
    for (int k = 1; k < cT; k++) mx = fmaxf(mx, av[k]);
    float ss = 0.0f;
#pragma unroll
    for (int k = 0; k < cT; k++) ss += __expf(av[k] - mx);
    const float afin = mx + __logf(ss) + ((lane < cT) ? cend[lane] : 0.0f);
    float dv[cT];
#pragma unroll
    for (int k = 0; k < cT; k++) dv[k] = __shfl(afin, k);
    float dmx = dv[0];
#pragma unroll
    for (int k = 1; k < cT; k++) dmx = fmaxf(dmx, dv[k]);
    float dss = 0.0f;
#pragma unroll
    for (int k = 0; k < cT; k++) dss += __expf(dv[k] - dmx);
    const float denom = dmx + __logf(dss);
    if (lane == 0) {
      const int l0 = lab[0];
      const float num = snum + cstart[l0] + eb[l0] + cend[lab[len - 1]];
      atomicAdd(out, (denom - num) * (1.0f / cB));
    }
  }
}

// ---------------- launch ----------------
extern "C" void kernel_launch(void* const* d_in, const int* in_sizes, int n_in,
                              void* d_out, int out_size, void* d_ws, size_t ws_size,
                              hipStream_t stream) {
  const float* word_emb = (const float*)d_in[0];
  const float* pos_emb = (const float*)d_in[1];
  const float* emb_ln_s = (const float*)d_in[2];
  const float* emb_ln_b = (const float*)d_in[3];
  const float* attn_qw = (const float*)d_in[4];
  const float* attn_qb = (const float*)d_in[5];
  const float* attn_kw = (const float*)d_in[6];
  const float* attn_kb = (const float*)d_in[7];
  const float* attn_vw = (const float*)d_in[8];
  const float* attn_vb = (const float*)d_in[9];
  const float* attn_ow = (const float*)d_in[10];
  const float* attn_ob = (const float*)d_in[11];
  const float* ln1_s = (const float*)d_in[12];
  const float* ln1_b = (const float*)d_in[13];
  const float* ffn_w1 = (const float*)d_in[14];
  const float* ffn_b1 = (const float*)d_in[15];
  const float* ffn_w2 = (const float*)d_in[16];
  const float* ffn_b2 = (const float*)d_in[17];
  const float* ln2_s = (const float*)d_in[18];
  const float* ln2_b = (const float*)d_in[19];
  const float* cls_w = (const float*)d_in[20];
  const float* cls_b = (const float*)d_in[21];
  const float* crf_start = (const float*)d_in[22];
  const float* crf_end = (const float*)d_in[23];
  const float* crf_trans = (const float*)d_in[24];
  const int* input_ids = (const int*)d_in[25];
  const int* amask = (const int*)d_in[26];
  const int* labels = (const int*)d_in[27];

  // ---- workspace layout (~191 MB total) ----
  char* ws = (char*)d_ws;
  size_t off = 0;
  auto alloc = [&](size_t bytes) -> void* {
    void* p = ws + off;
    off += (bytes + 255) & ~(size_t)255;
    return p;
  };
  constexpr size_t LW = 7077888;  // bf16 elems of one layer's transposed weights
  unsigned short* Wt = (unsigned short*)alloc(LW * 2);                  // 14.2 MB
  float* qkvb = (float*)alloc(cQS * 4);                                 // 9 KB
  float* x = (float*)alloc((size_t)cM * cH * 4);                        // 50.3 MB
  unsigned short* xb = (unsigned short*)alloc((size_t)cM * cH * 2);     // 25.2 MB
  unsigned short* un = (unsigned short*)alloc((size_t)cM * cFF * 2);    // 100.7 MB
  unsigned short* qkv = un;                       // cM x 2304 (attn phase)
  unsigned short* ctx = un + (size_t)cM * cQS;    // cM x 768
  unsigned short* hb = un;                        // cM x 3072 (FFN phase)
  float* emis = (float*)alloc((size_t)cM * cT * 4);                     // 0.5 MB

  hipMemsetAsync(d_out, 0, sizeof(float) * out_size, stream);

  embed_ln<<<cM, 256, 0, stream>>>(input_ids, word_emb, pos_emb, emb_ln_s, emb_ln_b, x, xb);

  for (int i = 0; i < cL; i++) {
    WtransArgs wa;
    wa.src[0] = attn_qw + (size_t)i * cH * cH;
    wa.src[1] = attn_kw + (size_t)i * cH * cH;
    wa.src[2] = attn_vw + (size_t)i * cH * cH;
    wa.src[3] = attn_ow + (size_t)i * cH * cH;
    wa.src[4] = ffn_w1 + (size_t)i * cH * cFF;
    wa.src[5] = ffn_w2 + (size_t)i * cFF * cH;
    wtrans_all<<<dim3(96, 24, 6), dim3(32, 8), 0, stream>>>(wa, Wt);
    concat_bias<<<9, 256, 0, stream>>>(attn_qb + i * cH, attn_kb + i * cH,
                                       attn_vb + i * cH, qkvb);

    gemm256<false, false, true><<<dim3(cQS / 256, cM / 256), 512, 0, stream>>>(
        xb, Wt, qkvb, nullptr, nullptr, qkv, cQS, cH);
    attn_mfma<<<cB * cNH * 4, 256, 0, stream>>>(qkv, amask, ctx);
    gemm256<true, false, false><<<dim3(cH / 256, cM / 256), 512, 0, stream>>>(
        ctx, Wt + 1769472, attn_ob + i * cH, x, x, nullptr, cH, cH);  // x += ctx@Wo+b
    ln_fused<<<cM, 256, 0, stream>>>(x, ln1_s + i * cH, ln1_b + i * cH, xb);
    gemm256<false, true, true><<<dim3(cFF / 256, cM / 256), 512, 0, stream>>>(
        xb, Wt + 2359296, ffn_b1 + i * cFF, nullptr, nullptr, hb, cFF, cH);
    gemm256<true, false, false><<<dim3(cH / 256, cM / 256), 512, 0, stream>>>(
        hb, Wt + 4718592, ffn_b2 + i * cH, x, x, nullptr, cH, cFF);   // x += h@W2+b
    ln_fused<<<cM, 256, 0, stream>>>(x, ln2_s + i * cH, ln2_b + i * cH, xb);
  }

  cls_head<<<cM / 4, 256, 0, stream>>>(x, cls_w, cls_b, emis);
  crf<<<cB, 1024, 0, stream>>>(emis, labels, crf_start, crf_end, crf_trans, (float*)d_out);
}